// Round 5
// baseline (699.097 us; speedup 1.0000x reference)
//
#include <hip/hip_runtime.h>

#define B 64
#define SLEN 768
#define NHID 1024
#define K2 2048
#define NTOK 32000
#define PADTOK (NTOK-1)
#define MAXL 16
#define MAXN 256
#define NINT 256
#define NCONV 128

typedef unsigned short u16;
typedef unsigned int u32;
typedef __attribute__((ext_vector_type(8))) short short8;
typedef __attribute__((ext_vector_type(4))) float f32x4;

__device__ __forceinline__ u16 f2b(float f) {
  union { float f; u32 i; } v; v.f = f;
  u32 x = v.i;
  return (u16)((x + 0x7FFFu + ((x >> 16) & 1u)) >> 16);
}
__device__ __forceinline__ float fast_tanh(float x) {
  float t = __expf(2.0f * x);
  return 1.0f - 2.0f / (t + 1.0f);
}
__device__ __forceinline__ void glds16(const void* g, void* l) {
  __builtin_amdgcn_global_load_lds(
      (const __attribute__((address_space(1))) void*)g,
      (__attribute__((address_space(3))) void*)l, 16, 0, 0);
}

// K-tiled + bank-swizzled layout (short index) for Apack and Wt:
//   128-row x 32-col blocks of 4096 shorts; within a block, the 8-short
//   chunk slot is XORed with (row>>1)&3 -> ds_read_b128 is 2-way (free).
// Rows 128-aligned per level (aoff aligned), cols = 2048 per row.
__device__ __forceinline__ size_t swz(int row, int col) {
  return ((size_t)((row >> 7) * 64 + (col >> 5)) << 12)
       + (size_t)(((row & 127) << 5)
       + (((((col >> 3) & 3) ^ ((row >> 1) & 3))) << 3)
       + (col & 7));
}

// ---------------------------------------------------------------------------
// Dispatch 1: block 0 = structural parse (batch-invariant) producing, for
// every node and leaf POSITION, its PARENT (level, slot, side) — so each
// level's producers scatter INTO the packed A-matrix of the consumer level.
// Blocks 1..NCONV: W fp32 -> bf16 in K-tiled swizzled layout (Wt).
// parentPacked = (lv<<20) | (slot<<4) | side;  -1 = root (no parent).
// ---------------------------------------------------------------------------
__launch_bounds__(768)
__global__ void parse_wt(const int* __restrict__ tokens,
                         const float* __restrict__ W,
                         int* __restrict__ cnt,       // [MAXL]
                         int* __restrict__ aoffG,     // [MAXL] packed-A row offsets (128-aligned)
                         int* __restrict__ rootArr,   // [1]
                         int* __restrict__ leafParG,  // [SLEN] position -> parentPacked
                         int* __restrict__ nodeMeta,  // [MAXL][MAXN] -> parentPacked / -1 root
                         u16* __restrict__ Wt) {
  if (blockIdx.x != 0) {
    // W conversion into tiled+swizzled layout
    int id = (blockIdx.x - 1) * 768 + threadIdx.x;
    int stride = NCONV * 768;
    for (int i = id; i < (NHID * K2) / 4; i += stride) {
      float4 v = reinterpret_cast<const float4*>(W)[i];
      int n = i >> 9;              // (i*4)/2048
      int k = (i << 2) & 2047;
      ushort4 o = {f2b(v.x), f2b(v.y), f2b(v.z), f2b(v.w)};
      *reinterpret_cast<ushort4*>(Wt + swz(n, k)) = o;
    }
    return;
  }

  // ---- block 0: parallel structural parse (batch 0; structure invariant) ----
  __shared__ int tok[SLEN];
  __shared__ int SC[SLEN];        // packed scan: depth<<20 | leaf<<10 | close
  __shared__ short A[16 * SLEN];  // per-depth max-scan; later lvl overlay
  __shared__ int cntLoc[MAXL];
  __shared__ int nodePar[NINT];   // nodeId -> parentPacked
  __shared__ int leafPar[SLEN];   // position -> parentPacked

  int t = threadIdx.x;
  tok[t] = tokens[t * B + 0];
  if (t < MAXL) cntLoc[t] = 0;
  if (t < NINT) nodePar[t] = -1;
  leafPar[t] = -1;
  __syncthreads();

  int tk = tok[t];
  bool isO = (tk == 0), isC = (tk == 1);
  bool isL = !isO && !isC && (tk != PADTOK);
  int delta = isO ? 1 : (isC ? -1 : 0);
  SC[t] = (delta << 20) + ((isL ? 1 : 0) << 10) + (isC ? 1 : 0);
  __syncthreads();

  for (int off = 1; off < SLEN; off <<= 1) {   // packed inclusive scan
    int v = SC[t];
    int u = (t >= off) ? SC[t - off] : 0;
    __syncthreads();
    SC[t] = v + u;
    __syncthreads();
  }

  int S = SC[t];
  int depth = S >> 20; if (depth > 15) depth = 15;
  int clIdx = S & 1023;

  // per-depth max scans: A[d][t] = max{t' <= t : D[t'] == d}, else -1
#pragma unroll
  for (int d = 0; d < 16; ++d) A[d * SLEN + t] = (depth == d) ? (short)t : (short)-1;
  __syncthreads();
  for (int off = 1; off < SLEN; off <<= 1) {
    short vv[16];
#pragma unroll
    for (int d = 0; d < 16; ++d) {
      short a = A[d * SLEN + t];
      if (t >= off) { short b2 = A[d * SLEN + t - off]; a = (a > b2) ? a : b2; }
      vv[d] = a;
    }
    __syncthreads();
#pragma unroll
    for (int d = 0; d < 16; ++d) A[d * SLEN + t] = vv[d];
    __syncthreads();
  }

  // per-CLOSE: children (leaf -> position, internal -> nodeId)
  int myid = -1, lce = -1, lNid = -1, rNid = -1;
  bool rIsLeaf = false, lIsLeaf = false;
  if (isC && t >= 3) {
    myid = clIdx - 1;
    rIsLeaf = (tok[t - 1] != 1);
    if (!rIsLeaf) rNid = (SC[t - 1] & 1023) - 1;
    int dd = depth + 1; if (dd > 15) dd = 15;
    lce = rIsLeaf ? (t - 2) : (int)A[dd * SLEN + (t - 2)];
    if (lce >= 0) {
      lIsLeaf = (tok[lce] != 1);
      if (!lIsLeaf) lNid = (SC[lce] & 1023) - 1;
    }
  }
  __syncthreads();

  // level sweeps (lvl overlays A row 0)
  short* lvl = A;
  lvl[t] = isC ? (short)1 : (short)0;
  __syncthreads();
  int lv = 1;
  for (int it = 0; it < 15; ++it) {
    if (myid >= 0) {
      int ll = lIsLeaf ? 0 : (lce >= 0 ? (int)lvl[lce] : 0);
      int rr = rIsLeaf ? 0 : (int)lvl[t - 1];
      lv = (ll > rr ? ll : rr) + 1;
    }
    __syncthreads();
    if (myid >= 0) lvl[t] = (short)lv;
    __syncthreads();
  }
  if (lv > 15) lv = 15;

  // bucket by level -> (lv, slot); then each node writes ITS (lv,slot,side)
  // into its children's parent records.
  int slot = -1;
  if (myid >= 0 && myid < NINT) slot = atomicAdd(&cntLoc[lv], 1);
  __syncthreads();
  if (slot >= 0 && slot < MAXN) {
    int pkL = (lv << 20) | (slot << 4);
    int pkR = pkL | 1;
    if (lce >= 0) {
      if (lIsLeaf) leafPar[lce] = pkL;
      else if (lNid >= 0 && lNid < NINT) nodePar[lNid] = pkL;
    }
    if (rIsLeaf) leafPar[t - 1] = pkR;
    else if (rNid >= 0 && rNid < NINT) nodePar[rNid] = pkR;
  }
  __syncthreads();
  if (slot >= 0 && slot < MAXN)
    nodeMeta[lv * MAXN + slot] = nodePar[myid];   // -1 for root
  leafParG[t] = leafPar[t];

  if (t == 0) {
    int ncount = SC[SLEN - 1] & 1023;
    rootArr[0] = (ncount > 0) ? 0 : 0x40000000;   // degenerate flag only
    int run = 0;
    for (int l = 1; l < MAXL; ++l) {
      int c = cntLoc[l] < MAXN ? cntLoc[l] : MAXN;
      cnt[l] = c;
      aoffG[l] = run;
      run += (B * c + 127) & ~127;                // 128-aligned per level
    }
  }
}

// ---------------------------------------------------------------------------
// Dispatch 2: scatter leaf embedding rows (bf16) into the packed A-matrix of
// each leaf's PARENT level, in the tiled+swizzled layout. Position-keyed.
// Degenerate single-leaf tree: copy emb row fp32 straight to out.
// ---------------------------------------------------------------------------
__global__ void leaf_scatter(const int* __restrict__ tokens,
                             const float* __restrict__ emb,
                             const int* __restrict__ leafPar,
                             const int* __restrict__ cnt,
                             const int* __restrict__ aoff,
                             const int* __restrict__ rootArr,
                             u16* __restrict__ Apack,
                             float* __restrict__ out) {
  int i4 = threadIdx.x * 4;
  bool deg = (rootArr[0] & 0x40000000) != 0;
  for (int r = blockIdx.x; r < B * SLEN; r += gridDim.x) {
    int b = r / SLEN, pos = r - b * SLEN;
    if (deg) {
      if (pos == 0) {
        int tk = tokens[0 * B + b];
        float4 v = *reinterpret_cast<const float4*>(emb + (size_t)tk * NHID + i4);
        *reinterpret_cast<float4*>(out + (size_t)b * NHID + i4) = v;
      }
      continue;
    }
    int pk = leafPar[pos];
    if (pk < 0) continue;                  // not a leaf position
    int tk = tokens[pos * B + b];
    int lvP = pk >> 20, sP = (pk >> 4) & 0xFFFF, side = pk & 1;
    int prow = aoff[lvP] + b * cnt[lvP] + sP;
    int col = (side << 10) + i4;
    float4 v = *reinterpret_cast<const float4*>(emb + (size_t)tk * NHID + i4);
    ushort4 o = {f2b(v.x), f2b(v.y), f2b(v.z), f2b(v.w)};
    *reinterpret_cast<ushort4*>(Apack + swz(prow, col)) = o;
  }
}

// ---------------------------------------------------------------------------
// Per-level combine: out = tanh(Apack_row @ W^T + b). 128x128 tile, 4 waves.
// A and W both pre-tiled+swizzled in global memory -> PURE LINEAR glds16
// staging (no gather, no pointer table) + conflict-free(2-way) ds_read_b128.
// 3 LDS buffers, depth-2 prefetch, counted vmcnt(4) waits.
// Epilogue scatters outputs into the PARENT level's packed A (and root->out).
// nt = tile&7 keeps each XCD on one W-stripe, L2-resident across all levels.
// ---------------------------------------------------------------------------
template<int LVL>
__launch_bounds__(256, 3)
__global__ void combine_lv(const u16* __restrict__ Wt,
                           const float* __restrict__ bias,
                           const int* __restrict__ cnt,
                           const int* __restrict__ aoff,
                           const int* __restrict__ nodeMeta,
                           u16* __restrict__ Apack,
                           float* __restrict__ out) {
  __shared__ short As[3][4096];
  __shared__ short Bs[3][4096];
  __shared__ int sPr[128];   // parent packed-A row; -1 root; -2 pad/skip
  __shared__ int sCs[128];   // col base (side<<10) or root out-offset

  int cnt0 = cnt[LVL];
  if (cnt0 <= 0) return;
  int aoffL = aoff[LVL];
  int rowsTotal = B * cnt0;
  int mTiles = (rowsTotal + 127) >> 7;
  int totalTiles = mTiles * 8;
  int tid = threadIdx.x;
  int lane = tid & 63, wave = tid >> 6;
  int wm = wave & 1, wn = wave >> 1;

  for (int tile = blockIdx.x; tile < totalTiles; tile += gridDim.x) {
    int mt = tile >> 3, nt = tile & 7;
    int m0 = mt << 7, n0 = nt << 7;
    __syncthreads();  // protect sPr/sCs vs previous tile's readers
    if (tid < 128) {
      int r = m0 + tid;
      int pr = -2, cs = 0;
      if (r < rowsTotal) {
        int bb = r / cnt0, j = r - bb * cnt0;
        int meta = nodeMeta[LVL * MAXN + j];
        if (meta < 0) { pr = -1; cs = bb * NHID; }
        else {
          int lvP = meta >> 20, sP = (meta >> 4) & 0xFFFF, side = meta & 1;
          pr = aoff[lvP] + bb * cnt[lvP] + sP;
          cs = side << 10;
        }
      }
      sPr[tid] = pr; sCs[tid] = cs;
    }
    __syncthreads();

    // tile base pointers in the tiled layout (aoffL, m0 both 128-aligned)
    const u16* Ab = Apack + ((size_t)(((aoffL + m0) >> 7) * 64) << 12);
    const u16* Bb = Wt + ((size_t)((n0 >> 7) * 64) << 12);
    int lofs = wave * 512 + lane * 8;

    f32x4 acc[4][4];
#pragma unroll
    for (int i = 0; i < 4; ++i)
#pragma unroll
      for (int j = 0; j < 4; ++j) acc[i][j] = {0.f, 0.f, 0.f, 0.f};

    // stage one 128x32 panel: 4 PURE-LINEAR wave loads (1 KB each)
    auto STAGE = [&](int buf, int kc) {
      const u16* sa = Ab + ((size_t)kc << 12) + lofs;
      const u16* sb = Bb + ((size_t)kc << 12) + lofs;
      short* Ad = &As[buf][0] + wave * 512;
      short* Bd = &Bs[buf][0] + wave * 512;
      glds16(sa, Ad);
      glds16(sa + 2048, Ad + 2048);
      glds16(sb, Bd);
      glds16(sb + 2048, Bd + 2048);
    };
    // compute one panel: 8 swizzled ds_read_b128 + 16 MFMA per thread
    auto COMPUTE = [&](int buf) {
      short8 af[4], bw[4];
      int q = lane >> 4;
#pragma unroll
      for (int mi = 0; mi < 4; ++mi) {
        int rA = wm * 64 + mi * 16 + (lane & 15);
        af[mi] = *reinterpret_cast<const short8*>(
            &As[buf][(rA << 5) + ((q ^ ((rA >> 1) & 3)) << 3)]);
      }
#pragma unroll
      for (int ni = 0; ni < 4; ++ni) {
        int rB = wn * 64 + ni * 16 + (lane & 15);
        bw[ni] = *reinterpret_cast<const short8*>(
            &Bs[buf][(rB << 5) + ((q ^ ((rB >> 1) & 3)) << 3)]);
      }
#pragma unroll
      for (int mi = 0; mi < 4; ++mi)
#pragma unroll
        for (int ni = 0; ni < 4; ++ni)
          acc[mi][ni] = __builtin_amdgcn_mfma_f32_16x16x32_bf16(
              af[mi], bw[ni], acc[mi][ni], 0, 0, 0);
    };

    // depth-2 / 3-buffer pipeline over 64 K-steps; counted waits (never 0
    // in the main loop): at each top-of-iter 8 loads outstanding, wait 4.
    STAGE(0, 0); STAGE(1, 1);
    int bc = 0, bs = 2;
    for (int t = 0; t < 62; ++t) {
      asm volatile("s_waitcnt vmcnt(4)" ::: "memory");
      __builtin_amdgcn_s_barrier();
      STAGE(bs, t + 2);
      COMPUTE(bc);
      bc = (bc == 2) ? 0 : bc + 1;
      bs = (bs == 2) ? 0 : bs + 1;
    }
    asm volatile("s_waitcnt vmcnt(4)" ::: "memory");
    __builtin_amdgcn_s_barrier();
    COMPUTE(bc);
    bc = (bc == 2) ? 0 : bc + 1;
    asm volatile("s_waitcnt vmcnt(0)" ::: "memory");
    __builtin_amdgcn_s_barrier();
    COMPUTE(bc);

    // epilogue: C/D layout col=lane&15 (n), row=(lane>>4)*4+reg (m)
#pragma unroll
    for (int ni = 0; ni < 4; ++ni) {
      int n = n0 + wn * 64 + ni * 16 + (lane & 15);
      float bv = bias[n];
#pragma unroll
      for (int mi = 0; mi < 4; ++mi) {
#pragma unroll
        for (int reg = 0; reg < 4; ++reg) {
          int mloc = wm * 64 + mi * 16 + (lane >> 4) * 4 + reg;
          int pr = sPr[mloc];
          if (pr != -2) {
            float v = fast_tanh(acc[mi][ni][reg] + bv);
            if (pr == -1) out[sCs[mloc] + n] = v;               // root -> fp32 out
            else Apack[swz(pr, sCs[mloc] + n)] = f2b(v);        // -> parent's A
          }
        }
      }
    }
  }
}

extern "C" void kernel_launch(void* const* d_in, const int* in_sizes, int n_in,
                              void* d_out, int out_size, void* d_ws, size_t ws_size,
                              hipStream_t stream) {
  const int* tokens = (const int*)d_in[0];
  const float* emb  = (const float*)d_in[1];
  const float* W    = (const float*)d_in[2];
  const float* bias = (const float*)d_in[3];
  float* out = (float*)d_out;

  char* ws = (char*)d_ws;
  // ws layout (bytes):
  //   cnt      @ 0        64 B
  //   rootArr  @ 4096     4 B
  //   aoff     @ 8192     64 B
  //   leafPar  @ 12288    3 KB
  //   nodeMeta @ 16384    16 KB
  //   Wt       @ 65536    4 MB   (K-tiled + swizzled bf16 W)
  //   Apack    @ 4259840  80 MB  (packed per-level A matrices, tiled+swizzled)
  int* cnt      = (int*)ws;
  int* rootArr  = (int*)(ws + 4096);
  int* aoff     = (int*)(ws + 8192);
  int* leafPar  = (int*)(ws + 12288);
  int* nodeMeta = (int*)(ws + 16384);
  u16* Wt       = (u16*)(ws + 65536);
  u16* Apack    = (u16*)(ws + 4259840);

  // D1: parse (block 0) + W tiling/conversion (blocks 1..NCONV), overlapped.
  parse_wt<<<1 + NCONV, 768, 0, stream>>>(tokens, W, cnt, aoff, rootArr,
                                          leafPar, nodeMeta, Wt);

  // D2: leaf rows -> packed A of each leaf's parent level.
  leaf_scatter<<<4096, 256, 0, stream>>>(tokens, emb, leafPar, cnt, aoff,
                                         rootArr, Apack, out);

  // D3..D10: one combine per level (levels 1..8 for the balanced 256-leaf
  // tree; grid-stride inside handles any actual distribution).
#define LAUNCH_LVL(L)                                                     \
  do {                                                                    \
    int expRows = B * (256 >> (L));                                       \
    int mT = (expRows + 127) / 128;                                       \
    combine_lv<L><<<mT * 8, 256, 0, stream>>>(Wt, bias, cnt, aoff,        \
                                              nodeMeta, Apack, out);      \
  } while (0)
  LAUNCH_LVL(1); LAUNCH_LVL(2); LAUNCH_LVL(3); LAUNCH_LVL(4);
  LAUNCH_LVL(5); LAUNCH_LVL(6); LAUNCH_LVL(7); LAUNCH_LVL(8);
#undef LAUNCH_LVL
}